// Round 1
// 230.849 us; speedup vs baseline: 1.0030x; 1.0030x over previous
//
#include <hip/hip_runtime.h>
#include <cmath>

#define C_CLASSES 21
#define EPS 1e-12f
#define IGNORE_INDEX (-1)
#define THREADS 256
#define EPT 8   // elements per thread
#define NC_LDS 4096

// native clang vectors so __builtin_nontemporal_load is legal (HIP int4/float4 are structs)
typedef int   v4i __attribute__((ext_vector_type(4)));
typedef float v4f __attribute__((ext_vector_type(4)));

// d_ws layout: [0 .. nblocks) float partial sums, then [nblocks .. 2*nblocks) int partial counts.
// Every block writes its own slot -> no zero-init dispatch needed, no atomics.

template <bool USE_LDS>
__global__ __launch_bounds__(THREADS) void pcl_reduce_kernel(
    const float* __restrict__ input,     // [N, 21] — only column 0, only for t==0 rows
    const float* __restrict__ weight,    // [N]
    const float* __restrict__ pc_input,  // [4096] — staged to LDS
    const int*   __restrict__ target,    // [N]
    const int*   __restrict__ cluster,   // [N]
    float* __restrict__ part_sum,        // [gridDim.x]
    int*   __restrict__ part_cnt,        // [gridDim.x]
    int n)
{
    // 16 KB: cluster-prob table in LDS -> ds_read gather instead of 57 L1 lines/wave/j
    __shared__ float spc[USE_LDS ? NC_LDS : 4];

    const int tid  = blockIdx.x * THREADS + threadIdx.x;
    const int base = tid * EPT;
    const bool full = (base + EPT - 1 < n);

    if (USE_LDS) {
#pragma unroll
        for (int k = 0; k < NC_LDS; k += THREADS * 4) {
            const int idx = k + (threadIdx.x << 2);   // 256 thr * 4 floats, 4 passes
            *reinterpret_cast<v4f*>(&spc[idx]) =
                *reinterpret_cast<const v4f*>(pc_input + idx);
        }
    }

    // issue the streaming loads before the barrier so HBM latency overlaps the staging drain
    v4i t0 = {0,0,0,0}, t1 = {0,0,0,0}, c0 = {0,0,0,0}, c1 = {0,0,0,0};
    v4f w0 = {0,0,0,0}, w1 = {0,0,0,0};
    if (full) {
        const v4i* tp = reinterpret_cast<const v4i*>(target + base);
        const v4i* cp = reinterpret_cast<const v4i*>(cluster + base);
        const v4f* wp = reinterpret_cast<const v4f*>(weight + base);
        t0 = __builtin_nontemporal_load(tp);       // single-touch streams: nt, keep L2 clean
        t1 = __builtin_nontemporal_load(tp + 1);
        c0 = __builtin_nontemporal_load(cp);
        c1 = __builtin_nontemporal_load(cp + 1);
        w0 = __builtin_nontemporal_load(wp);
        w1 = __builtin_nontemporal_load(wp + 1);
    }

    if (USE_LDS) __syncthreads();   // uniform point (outside divergent full/tail paths)

    float lsum = 0.0f;
    int   lcnt = 0;

    if (full) {
        const int   ts[EPT] = {t0[0], t0[1], t0[2], t0[3], t1[0], t1[1], t1[2], t1[3]};
        const int   cs[EPT] = {c0[0], c0[1], c0[2], c0[3], c1[0], c1[1], c1[2], c1[3]};
        const float wv[EPT] = {w0[0], w0[1], w0[2], w0[3], w1[0], w1[1], w1[2], w1[3]};

#pragma unroll
        for (int j = 0; j < EPT; ++j) {
            const int t = ts[j];
            if (t == IGNORE_INDEX) continue;
            ++lcnt;
            float p;
            if (t == 0) {
                // background: scattered predicated load, ~1/21 of lanes
                p = input[(size_t)(base + j) * C_CLASSES];
            } else {
                // foreground: LDS gather (random banks, ~2-6 way, far cheaper than L1 gather)
                p = USE_LDS ? spc[cs[j]] : pc_input[cs[j]];
            }
            lsum -= wv[j] * logf(fmaxf(p, EPS));
        }
    } else if (base < n) {
        for (int j = 0; j < EPT && base + j < n; ++j) {
            const int i = base + j;
            const int t = target[i];
            if (t == IGNORE_INDEX) continue;
            ++lcnt;
            float p = (t == 0) ? input[(size_t)i * C_CLASSES]
                               : (USE_LDS ? spc[cluster[i]] : pc_input[cluster[i]]);
            lsum -= weight[i] * logf(fmaxf(p, EPS));
        }
    }

    // wave64 shuffle reduction
#pragma unroll
    for (int off = 32; off > 0; off >>= 1) {
        lsum += __shfl_down(lsum, off, 64);
        lcnt += __shfl_down(lcnt, off, 64);
    }

    __shared__ float ssum[THREADS / 64];
    __shared__ int   scnt[THREADS / 64];
    const int wave = threadIdx.x >> 6;
    const int lane = threadIdx.x & 63;
    if (lane == 0) { ssum[wave] = lsum; scnt[wave] = lcnt; }
    __syncthreads();

    if (threadIdx.x == 0) {
        float bs = 0.0f; int bc = 0;
#pragma unroll
        for (int w = 0; w < THREADS / 64; ++w) { bs += ssum[w]; bc += scnt[w]; }
        part_sum[blockIdx.x] = bs;
        part_cnt[blockIdx.x] = bc;
    }
}

__global__ __launch_bounds__(THREADS) void pcl_finalize_kernel(
    const float* __restrict__ part_sum,
    const int*   __restrict__ part_cnt,
    float* __restrict__ out,
    int nblocks)
{
    double lsum = 0.0;
    long long lcnt = 0;
    for (int i = threadIdx.x; i < nblocks; i += THREADS) {
        lsum += (double)part_sum[i];
        lcnt += part_cnt[i];
    }
#pragma unroll
    for (int off = 32; off > 0; off >>= 1) {
        lsum += __shfl_down(lsum, off, 64);
        lcnt += __shfl_down(lcnt, off, 64);
    }
    __shared__ double ssum[THREADS / 64];
    __shared__ long long scnt[THREADS / 64];
    const int wave = threadIdx.x >> 6;
    const int lane = threadIdx.x & 63;
    if (lane == 0) { ssum[wave] = lsum; scnt[wave] = lcnt; }
    __syncthreads();
    if (threadIdx.x == 0) {
        double s = 0.0; long long c = 0;
#pragma unroll
        for (int w = 0; w < THREADS / 64; ++w) { s += ssum[w]; c += scnt[w]; }
        double denom = (double)c;
        if (denom < 1.0) denom = 1.0;
        out[0] = (float)(s / denom);
    }
}

extern "C" void kernel_launch(void* const* d_in, const int* in_sizes, int n_in,
                              void* d_out, int out_size, void* d_ws, size_t ws_size,
                              hipStream_t stream) {
    const float* input    = (const float*)d_in[0];
    const float* weight   = (const float*)d_in[1];
    const float* pc_input = (const float*)d_in[2];
    const int*   target   = (const int*)d_in[3];
    const int*   cluster  = (const int*)d_in[4];
    float* out = (float*)d_out;

    const int n    = in_sizes[1];  // weight has N elements
    const int pc_n = in_sizes[2];  // cluster-prob table size

    const int groups = (n + EPT - 1) / EPT;
    const int blocks = (groups + THREADS - 1) / THREADS;  // 1024 for N=2^21

    float* part_sum = (float*)d_ws;
    int*   part_cnt = (int*)((char*)d_ws + (size_t)blocks * sizeof(float));

    if (pc_n == NC_LDS) {
        pcl_reduce_kernel<true><<<blocks, THREADS, 0, stream>>>(
            input, weight, pc_input, target, cluster, part_sum, part_cnt, n);
    } else {
        pcl_reduce_kernel<false><<<blocks, THREADS, 0, stream>>>(
            input, weight, pc_input, target, cluster, part_sum, part_cnt, n);
    }

    pcl_finalize_kernel<<<1, THREADS, 0, stream>>>(part_sum, part_cnt, out, blocks);
}